// Round 10
// baseline (635.057 us; speedup 1.0000x reference)
//
#include <hip/hip_runtime.h>

typedef __attribute__((ext_vector_type(4))) float f32x4;
typedef __attribute__((ext_vector_type(16))) float f32x16;
typedef __attribute__((ext_vector_type(8))) short s16x8;
typedef __attribute__((ext_vector_type(4))) unsigned short u16x4;
typedef __attribute__((ext_vector_type(4))) unsigned int u32x4;

#define DEV __device__ __forceinline__

DEV unsigned short f2bf(float f) {
  unsigned int u = __float_as_uint(f);
  return (unsigned short)((u + 0x7FFFu + ((u >> 16) & 1u)) >> 16);
}

DEV float exp2_asm(float x) {        // v_exp_f32: D = 2^S0
  float r; asm("v_exp_f32 %0, %1" : "=v"(r) : "v"(x)); return r;
}
DEV float rcp_asm(float x) {
  float r; asm("v_rcp_f32 %0, %1" : "=v"(r) : "v"(x)); return r;
}
// pack two f32 -> bf16x2 word (truncating; P bounded, tolerance-safe per R8)
DEV unsigned int pk2(float a, float b) {
  return (__float_as_uint(b) & 0xFFFF0000u) | (__float_as_uint(a) >> 16);
}
// v_permlane32_swap_b32: X.lanes[32:63] <-> Y.lanes[0:31]
DEV void pl32swap(unsigned int& x, unsigned int& y) {
  asm volatile("v_permlane32_swap_b32 %0, %1" : "+v"(x), "+v"(y));
}

DEV void gload_lds16(const void* g, void* l) {
  __builtin_amdgcn_global_load_lds(
      (const __attribute__((address_space(1))) unsigned int*)g,
      (__attribute__((address_space(3))) unsigned int*)l, 16, 0, 0);
}

// ---------------- LayerNorm: fp32 in -> bf16 out (rows of 1024) ----------------
__global__ __launch_bounds__(256) void ln_kernel(
    const float* __restrict__ x, const float* __restrict__ gam,
    const float* __restrict__ bet, unsigned short* __restrict__ o)
{
  const int row = blockIdx.x;
  const int tid = threadIdx.x;
  f32x4 v = *(const f32x4*)(x + (size_t)row * 1024 + tid * 4);
  float s = v[0] + v[1] + v[2] + v[3];
  float s2 = v[0]*v[0] + v[1]*v[1] + v[2]*v[2] + v[3]*v[3];
  #pragma unroll
  for (int m = 1; m < 64; m <<= 1) { s += __shfl_xor(s, m); s2 += __shfl_xor(s2, m); }
  __shared__ float ps[4], ps2[4];
  const int wid = tid >> 6, lane = tid & 63;
  if (lane == 0) { ps[wid] = s; ps2[wid] = s2; }
  __syncthreads();
  s = ps[0] + ps[1] + ps[2] + ps[3];
  s2 = ps2[0] + ps2[1] + ps2[2] + ps2[3];
  const float mu = s * (1.0f / 1024.0f);
  const float rstd = rsqrtf(s2 * (1.0f / 1024.0f) - mu * mu + 1e-5f);
  f32x4 g4 = *(const f32x4*)(gam + tid * 4);
  f32x4 b4 = *(const f32x4*)(bet + tid * 4);
  u16x4 ov;
  #pragma unroll
  for (int j = 0; j < 4; j++) ov[j] = f2bf((v[j] - mu) * rstd * g4[j] + b4[j]);
  *(u16x4*)(o + (size_t)row * 1024 + tid * 4) = ov;
}

// -------- transpose+convert: W[K][N] f32 -> WT[N][K] bf16 (64x64 LDS tiles) --------
__global__ __launch_bounds__(256) void transpose_kernel(
    const float* __restrict__ W, unsigned short* __restrict__ WT, int K, int N)
{
  __shared__ float tile[64][65];
  const int n0 = blockIdx.x * 64, k0 = blockIdx.y * 64;
  const int c = threadIdx.x & 63, r0 = threadIdx.x >> 6;
  #pragma unroll
  for (int r = r0; r < 64; r += 4)
    tile[r][c] = W[(size_t)(k0 + r) * N + n0 + c];
  __syncthreads();
  #pragma unroll
  for (int r = r0; r < 64; r += 4)
    WT[(size_t)(n0 + r) * K + k0 + c] = f2bf(tile[c][r]);
}

// --- 128x256 GEMM, BK=64, XOR-swizzled LDS, 3-slot ring, ONE barrier/K-tile ---
// MODE 0: out bf16, cols<1024 pre-scaled by 0.125*log2e (Q for attn);
// MODE 1: out f32 = v + resid; MODE 2: out bf16 = gelu(v)
template <int MODE>
__global__ __launch_bounds__(512) void gemm8_kernel(
    const unsigned short* __restrict__ A, const unsigned short* __restrict__ WT,
    const float* __restrict__ bias, const float* resid, void* outp,
    int M, int N, int K)
{
  __shared__ unsigned short lds[3 * 24576];   // slot: A 128x64 (16KB) + B 256x64 (32KB)
  const int tid = threadIdx.x;
  const int lane = tid & 63, wid = tid >> 6;
  const int l15 = lane & 15, l4 = lane >> 4;
  const int wm = wid >> 2, wn = wid & 3;
  const int tiles_n = N >> 8;
  const int cpx = gridDim.x >> 3;
  const int id = (blockIdx.x & 7) * cpx + (blockIdx.x >> 3);
  const int bm = id / tiles_n, bn = id % tiles_n;
  const int NT = K >> 6;

  const int srow = tid >> 3;
  const int scol = ((tid & 7) ^ (srow & 7)) * 8;
  const unsigned short* Asrc = A  + (size_t)(bm * 128 + srow) * K + scol;
  const unsigned short* Bsrc = WT + (size_t)(bn * 256 + srow) * K + scol;
  const size_t j64 = (size_t)64 * K;
  const int dwave = wid * 1024;

#define STAGE(t_, ss_) do { \
    char* base_ = (char*)lds + (ss_) * 49152 + dwave; \
    const unsigned short* sA_ = Asrc + (size_t)(t_) * 64; \
    const unsigned short* sB_ = Bsrc + (size_t)(t_) * 64; \
    gload_lds16(sA_,            base_); \
    gload_lds16(sA_ + j64,      base_ + 8192); \
    gload_lds16(sB_,            base_ + 16384); \
    gload_lds16(sB_ + j64,      base_ + 16384 + 8192); \
    gload_lds16(sB_ + 2 * j64,  base_ + 16384 + 16384); \
    gload_lds16(sB_ + 3 * j64,  base_ + 16384 + 24576); \
  } while (0)

  f32x4 acc[4][4] = {};

  const int arow0 = wm * 64 + l15;
  const int brow0 = wn * 64 + l15;
  const int cswz = l15 & 7;

  STAGE(0, 0);
  STAGE(1, 1);
  asm volatile("s_waitcnt vmcnt(6)" ::: "memory");
  __builtin_amdgcn_s_barrier();

  int cs = 0, ss = 2;
  for (int t = 0; t < NT; ++t) {
    const unsigned short* sa = lds + cs * 24576;
    const unsigned short* sb = sa + 8192;
    s16x8 af[4][2], bf[4][2];
    #pragma unroll
    for (int mf = 0; mf < 4; ++mf)
      #pragma unroll
      for (int ks = 0; ks < 2; ++ks)
        af[mf][ks] = *(const s16x8*)&sa[(arow0 + mf * 16) * 64 + (((ks * 4 + l4) ^ cswz) * 8)];
    #pragma unroll
    for (int nf = 0; nf < 4; ++nf)
      #pragma unroll
      for (int ks = 0; ks < 2; ++ks)
        bf[nf][ks] = *(const s16x8*)&sb[(brow0 + nf * 16) * 64 + (((ks * 4 + l4) ^ cswz) * 8)];
    if (t + 2 < NT) STAGE(t + 2, ss);
    __builtin_amdgcn_s_setprio(1);
    #pragma unroll
    for (int mf = 0; mf < 4; ++mf)
      #pragma unroll
      for (int nf = 0; nf < 4; ++nf)
        #pragma unroll
        for (int ks = 0; ks < 2; ++ks)
          acc[mf][nf] = __builtin_amdgcn_mfma_f32_16x16x32_bf16(
              af[mf][ks], bf[nf][ks], acc[mf][nf], 0, 0, 0);
    __builtin_amdgcn_s_setprio(0);
    if (t + 2 < NT)      { asm volatile("s_waitcnt vmcnt(6)" ::: "memory"); }
    else if (t + 1 < NT) { asm volatile("s_waitcnt vmcnt(0)" ::: "memory"); }
    __builtin_amdgcn_s_barrier();
    cs = (cs == 2) ? 0 : cs + 1;
    ss = (ss == 2) ? 0 : ss + 1;
  }
#undef STAGE

  #pragma unroll
  for (int nf = 0; nf < 4; nf++) {
    const int col = bn * 256 + wn * 64 + nf * 16 + l15;
    const float bv = bias[col];
    const float qs = (MODE == 0 && col < 1024) ? 0.18033688f : 1.0f;  // Q pre-scale
    #pragma unroll
    for (int mf = 0; mf < 4; mf++) {
      #pragma unroll
      for (int r = 0; r < 4; r++) {
        const int row = bm * 128 + wm * 64 + mf * 16 + l4 * 4 + r;
        const size_t off = (size_t)row * N + col;
        float v = acc[mf][nf][r] + bv;
        if (MODE == 1) {
          ((float*)outp)[off] = v + resid[off];
        } else if (MODE == 2) {
          const float u = v + 0.044715f * v * v * v;
          const float e = exp2_asm(-2.3022010f * u);
          ((unsigned short*)outp)[off] = f2bf(v * rcp_asm(1.0f + e));
        } else {
          ((unsigned short*)outp)[off] = f2bf(v * qs);
        }
      }
    }
  }
}

// ---------------- causal flash attention (R10: 32x32 MFMA, adjacent pairing) ------
// Wave w owns 32 q-rows: w0,w1 -> qA halves; w2,w3 -> qB halves.
// R10: qA=2*pid, qB=2*pid+1 (adjacent) -> waves idle only on the single
// diagonal round; total block-rounds per (b,h) drop 392 -> 272. 6 blocks/CU
// for backfill of now-variable block lengths.
__global__ __launch_bounds__(256, 6) void attn_kernel(
    const unsigned short* __restrict__ qkv, unsigned short* __restrict__ outb)
{
  __shared__ unsigned short Ks[2][64 * 64];       // [kv][d^((kv&7)<<3)], double-buffered
  __shared__ unsigned short Vt[64 * 64];          // [d][kv^(((d>>2)&7)<<3)]
  __shared__ float alf[4][32];                    // per-wave alpha/invl transpose slot
  const int pid = blockIdx.x;                     // 0..15
  const int qA = 2 * pid, qB = 2 * pid + 1;       // adjacent q-tile pair
  const int bh = blockIdx.y;
  const int b = bh >> 4, h = bh & 15;
  const int tid = threadIdx.x, lane = tid & 63, wid = tid >> 6;
  const int l31 = lane & 31, hi = lane >> 5;
  const int myq = (wid < 2) ? qA : qB;
  const int qbase = myq * 64 + (wid & 1) * 32;    // first of this wave's 32 rows
  const size_t base = (size_t)b * 2048 * 3072 + (size_t)h * 64;
  const unsigned short* Qb = qkv + base;
  const unsigned short* Kb = qkv + base + 1024;
  const unsigned short* Vb = qkv + base + 2048;

  // Q fragments: chunk c -> Q[qbase+l31][c*16 + hi*8 .. +8] (pre-scaled upstream)
  s16x8 qf[4];
  {
    const unsigned short* qr = Qb + (size_t)(qbase + l31) * 3072 + hi * 8;
    qf[0] = *(const s16x8*)(qr);
    qf[1] = *(const s16x8*)(qr + 16);
    qf[2] = *(const s16x8*)(qr + 32);
    qf[3] = *(const s16x8*)(qr + 48);
  }

  // prologue: V(0) reg loads FIRST, then K(0) gload_lds (vmcnt counts rely on order)
  u16x4 vv[4];
  #pragma unroll
  for (int it = 0; it < 4; ++it) {
    const int cc = tid + 256 * it;
    vv[it] = *(const u16x4*)(Vb + (size_t)(cc >> 4) * 3072 + (cc & 15) * 4);
  }
  #pragma unroll
  for (int s = 0; s < 2; ++s) {
    const int c = s * 256 + tid;
    const int kv = c >> 3;
    const int dsrc = ((c & 7) * 8) ^ ((kv & 7) << 3);
    gload_lds16(Kb + (size_t)kv * 3072 + dsrc, &Ks[0][(size_t)(c & ~63) * 8]);
  }

  f32x16 o0 = {0,0,0,0,0,0,0,0,0,0,0,0,0,0,0,0};
  f32x16 o1 = {0,0,0,0,0,0,0,0,0,0,0,0,0,0,0,0};
  float m = -1e30f, lsum = 0.f;

  for (int kvb = 0; kvb <= qB; ++kvb) {
    const int cur = kvb & 1;
    const int kv0 = kvb * 64;
    __builtin_amdgcn_s_barrier();                 // #1: prev tile fully consumed
    asm volatile("s_waitcnt vmcnt(2)" ::: "memory");   // V(kvb) regs landed; K(kvb) flying
    #pragma unroll
    for (int it = 0; it < 4; ++it) {
      const int cc = tid + 256 * it;
      const int vkv = cc >> 4;
      const int vd = (cc & 15) * 4;
      #pragma unroll
      for (int j = 0; j < 4; j++) {
        const int d = vd + j;
        Vt[d * 64 + (vkv ^ (((d >> 2) & 7) << 3))] = vv[it][j];
      }
    }
    if (kvb < qB) {
      #pragma unroll
      for (int it = 0; it < 4; ++it) {
        const int cc = tid + 256 * it;
        vv[it] = *(const u16x4*)(Vb + (size_t)((kvb + 1) * 64 + (cc >> 4)) * 3072 + (cc & 15) * 4);
      }
      asm volatile("s_waitcnt vmcnt(4)" ::: "memory");  // K(kvb) landed; V(kvb+1) flying
    } else {
      asm volatile("s_waitcnt vmcnt(0)" ::: "memory");
    }
    asm volatile("s_waitcnt lgkmcnt(0)" ::: "memory");  // Vt ds_writes drained
    __builtin_amdgcn_s_barrier();                 // #2: Ks[cur], Vt published
    if (kvb < qB) {
      #pragma unroll
      for (int s = 0; s < 2; ++s) {
        const int c = s * 256 + tid;
        const int kv = c >> 3;
        const int dsrc = ((c & 7) * 8) ^ ((kv & 7) << 3);
        gload_lds16(Kb + (size_t)((kvb + 1) * 64 + kv) * 3072 + dsrc,
                    &Ks[cur ^ 1][(size_t)(c & ~63) * 8]);
      }
    }

    if (kvb <= myq) {                             // wave-uniform compute gate
      const unsigned short* Kc = Ks[cur];
      // ---- QK^T: S^T[kv][q], lane=(q=l31,hi); reg r -> kv=(r&3)+8(r>>2)+4hi (+32 for s1)
      f32x16 s0 = {0,0,0,0,0,0,0,0,0,0,0,0,0,0,0,0};
      f32x16 s1 = {0,0,0,0,0,0,0,0,0,0,0,0,0,0,0,0};
      __builtin_amdgcn_s_setprio(1);
      #pragma unroll
      for (int c = 0; c < 4; ++c) {
        const int koff = ((2 * c + hi) ^ (l31 & 7)) * 8;
        s16x8 k0 = *(const s16x8*)&Kc[l31 * 64 + koff];
        s16x8 k1 = *(const s16x8*)&Kc[(32 + l31) * 64 + koff];
        s0 = __builtin_amdgcn_mfma_f32_32x32x16_bf16(k0, qf[c], s0, 0, 0, 0);
        s1 = __builtin_amdgcn_mfma_f32_32x32x16_bf16(k1, qf[c], s1, 0, 0, 0);
      }
      __builtin_amdgcn_s_setprio(0);
      // ---- mask (diagonal tiles only; wave-uniform branch)
      if (kv0 + 63 > qbase) {
        const int thr = qbase + l31 - kv0;        // mask if kv_local > thr
        #pragma unroll
        for (int r = 0; r < 16; ++r) {
          const int kvl = (r & 3) + 8 * (r >> 2) + 4 * hi;
          if (kvl > thr)      s0[r] = -3.0e38f;
          if (kvl + 32 > thr) s1[r] = -3.0e38f;
        }
      }
      // ---- online softmax (log2 domain; in-lane + one shfl)
      float mx = s0[0];
      #pragma unroll
      for (int r = 1; r < 16; ++r) mx = fmaxf(mx, s0[r]);
      #pragma unroll
      for (int r = 0; r < 16; ++r) mx = fmaxf(mx, s1[r]);
      mx = fmaxf(mx, __shfl_xor(mx, 32));
      const bool skip = __all(mx <= m + 11.5f);   // defer-max
      const float mnew = skip ? m : fmaxf(m, mx);
      float rsum = 0.f;
      #pragma unroll
      for (int r = 0; r < 16; ++r) { s0[r] = exp2_asm(s0[r] - mnew); rsum += s0[r]; }
      #pragma unroll
      for (int r = 0; r < 16; ++r) { s1[r] = exp2_asm(s1[r] - mnew); rsum += s1[r]; }
      rsum += __shfl_xor(rsum, 32);
      if (skip) {
        lsum += rsum;
      } else {
        const float alpha = exp2_asm(m - mnew);
        lsum = lsum * alpha + rsum;
        m = mnew;
        alf[wid][l31] = alpha;                    // transpose q->reg via LDS (rare)
        #pragma unroll
        for (int r = 0; r < 16; ++r) {
          const float ar = alf[wid][(r & 3) + 8 * (r >> 2) + 4 * hi];
          o0[r] *= ar; o1[r] *= ar;
        }
      }
      // ---- P -> PV A-fragments via pack + permlane32_swap (T12)
      s16x8 pa[4];
      #pragma unroll
      for (int kb = 0; kb < 2; ++kb) {
        #pragma unroll
        for (int cc = 0; cc < 2; ++cc) {
          const int rb = cc * 8;
          unsigned int X0, Y0, X1, Y1;
          if (kb == 0) {
            X0 = pk2(s0[rb + 0], s0[rb + 1]); Y0 = pk2(s0[rb + 4], s0[rb + 5]);
            X1 = pk2(s0[rb + 2], s0[rb + 3]); Y1 = pk2(s0[rb + 6], s0[rb + 7]);
          } else {
            X0 = pk2(s1[rb + 0], s1[rb + 1]); Y0 = pk2(s1[rb + 4], s1[rb + 5]);
            X1 = pk2(s1[rb + 2], s1[rb + 3]); Y1 = pk2(s1[rb + 6], s1[rb + 7]);
          }
          pl32swap(X0, Y0);                       // -> words w0, w2
          pl32swap(X1, Y1);                       // -> words w1, w3
          u32x4 w = {X0, X1, Y0, Y1};
          pa[kb * 2 + cc] = __builtin_bit_cast(s16x8, w);
        }
      }
      // ---- PV: O[q][d], lane=(d=l31,hi); A=pa (row=q,k=kv), B=Vt frag (col=d,k=kv)
      const int voff = l31 >> 2;                  // (d>>2)&7, same for both d-blocks
      __builtin_amdgcn_s_setprio(1);
      #pragma unroll
      for (int c = 0; c < 4; ++c) {
        const int off = ((2 * c + hi) ^ voff) * 8;
        s16x8 v0 = *(const s16x8*)&Vt[l31 * 64 + off];
        s16x8 v1 = *(const s16x8*)&Vt[(32 + l31) * 64 + off];
        o0 = __builtin_amdgcn_mfma_f32_32x32x16_bf16(pa[c], v0, o0, 0, 0, 0);
        o1 = __builtin_amdgcn_mfma_f32_32x32x16_bf16(pa[c], v1, o1, 0, 0, 0);
      }
      __builtin_amdgcn_s_setprio(0);
    }
  }

  // ---- normalize + write: lane=(d=l31,hi); q per reg via LDS transpose
  const float iv = rcp_asm(lsum);
  alf[wid][l31] = iv;
  unsigned short* ob = outb + ((size_t)b * 2048 + qbase) * 1024 + h * 64 + l31;
  #pragma unroll
  for (int r = 0; r < 16; ++r) {
    const int ql = (r & 3) + 8 * (r >> 2) + 4 * hi;
    const float ir = alf[wid][ql];
    ob[(size_t)ql * 1024]      = f2bf(o0[r] * ir);
    ob[(size_t)ql * 1024 + 32] = f2bf(o1[r] * ir);
  }
}

// ---------------- host ----------------
extern "C" void kernel_launch(void* const* d_in, const int* in_sizes, int n_in,
                              void* d_out, int out_size, void* d_ws, size_t ws_size,
                              hipStream_t stream) {
  const float* x      = (const float*)d_in[0];
  const float* ln1_g  = (const float*)d_in[1];
  const float* ln1_b  = (const float*)d_in[2];
  const float* qkv_w  = (const float*)d_in[3];
  const float* qkv_b  = (const float*)d_in[4];
  const float* proj_w = (const float*)d_in[5];
  const float* proj_b = (const float*)d_in[6];
  const float* ln2_g  = (const float*)d_in[7];
  const float* ln2_b  = (const float*)d_in[8];
  const float* ff1_w  = (const float*)d_in[9];
  const float* ff1_b  = (const float*)d_in[10];
  const float* ff2_w  = (const float*)d_in[11];
  const float* ff2_b  = (const float*)d_in[12];
  float* out = (float*)d_out;

  char* ws = (char*)d_ws;
  size_t off = 0;
  unsigned short* wbuf   = (unsigned short*)(ws + off); off += (size_t)4096 * 1024 * 2;  // 8 MiB
  unsigned short* hbuf   = (unsigned short*)(ws + off); off += (size_t)8192 * 1024 * 2;  // 16 MiB
  unsigned short* qkvbuf = (unsigned short*)(ws + off); off += (size_t)8192 * 3072 * 2;  // 48 MiB
  unsigned short* gbuf   = (unsigned short*)(ws + off);                                   // 64 MiB

  // ---- attention sublayer ----
  ln_kernel<<<8192, 256, 0, stream>>>(x, ln1_g, ln1_b, hbuf);
  transpose_kernel<<<dim3(3072 / 64, 1024 / 64), 256, 0, stream>>>(qkv_w, wbuf, 1024, 3072);
  gemm8_kernel<0><<<dim3(64 * 12), 512, 0, stream>>>(hbuf, wbuf, qkv_b, nullptr, qkvbuf,
                                                     8192, 3072, 1024);
  attn_kernel<<<dim3(16, 64), 256, 0, stream>>>(qkvbuf, hbuf);
  transpose_kernel<<<dim3(1024 / 64, 1024 / 64), 256, 0, stream>>>(proj_w, wbuf, 1024, 1024);
  gemm8_kernel<1><<<dim3(64 * 4), 512, 0, stream>>>(hbuf, wbuf, proj_b, x, out,
                                                    8192, 1024, 1024);   // x1 -> d_out (f32)
  // ---- MLP sublayer ----
  ln_kernel<<<8192, 256, 0, stream>>>(out, ln2_g, ln2_b, hbuf);
  transpose_kernel<<<dim3(4096 / 64, 1024 / 64), 256, 0, stream>>>(ff1_w, wbuf, 1024, 4096);
  gemm8_kernel<2><<<dim3(64 * 16), 512, 0, stream>>>(hbuf, wbuf, ff1_b, nullptr, gbuf,
                                                     8192, 4096, 1024);  // gelu
  transpose_kernel<<<dim3(1024 / 64, 4096 / 64), 256, 0, stream>>>(ff2_w, wbuf, 4096, 1024);
  gemm8_kernel<1><<<dim3(64 * 4), 512, 0, stream>>>(gbuf, wbuf, ff2_b, out, out,
                                                    8192, 1024, 4096);   // + x1 in-place
}

// Round 11
// 469.941 us; speedup vs baseline: 1.3514x; 1.3514x over previous
//
#include <hip/hip_runtime.h>

typedef __attribute__((ext_vector_type(4))) float f32x4;
typedef __attribute__((ext_vector_type(16))) float f32x16;
typedef __attribute__((ext_vector_type(8))) short s16x8;
typedef __attribute__((ext_vector_type(4))) unsigned short u16x4;
typedef __attribute__((ext_vector_type(4))) unsigned int u32x4;

#define DEV __device__ __forceinline__

DEV unsigned short f2bf(float f) {
  unsigned int u = __float_as_uint(f);
  return (unsigned short)((u + 0x7FFFu + ((u >> 16) & 1u)) >> 16);
}

DEV float exp2_asm(float x) {        // v_exp_f32: D = 2^S0
  float r; asm("v_exp_f32 %0, %1" : "=v"(r) : "v"(x)); return r;
}
DEV float rcp_asm(float x) {
  float r; asm("v_rcp_f32 %0, %1" : "=v"(r) : "v"(x)); return r;
}
// pack two f32 -> bf16x2 word (truncating; P bounded, tolerance-safe per R8)
DEV unsigned int pk2(float a, float b) {
  return (__float_as_uint(b) & 0xFFFF0000u) | (__float_as_uint(a) >> 16);
}
// v_permlane32_swap_b32: X.lanes[32:63] <-> Y.lanes[0:31]
DEV void pl32swap(unsigned int& x, unsigned int& y) {
  asm volatile("v_permlane32_swap_b32 %0, %1" : "+v"(x), "+v"(y));
}

DEV void gload_lds16(const void* g, void* l) {
  __builtin_amdgcn_global_load_lds(
      (const __attribute__((address_space(1))) unsigned int*)g,
      (__attribute__((address_space(3))) unsigned int*)l, 16, 0, 0);
}

// ---------------- LayerNorm: fp32 in -> bf16 out (rows of 1024) ----------------
__global__ __launch_bounds__(256) void ln_kernel(
    const float* __restrict__ x, const float* __restrict__ gam,
    const float* __restrict__ bet, unsigned short* __restrict__ o)
{
  const int row = blockIdx.x;
  const int tid = threadIdx.x;
  f32x4 v = *(const f32x4*)(x + (size_t)row * 1024 + tid * 4);
  float s = v[0] + v[1] + v[2] + v[3];
  float s2 = v[0]*v[0] + v[1]*v[1] + v[2]*v[2] + v[3]*v[3];
  #pragma unroll
  for (int m = 1; m < 64; m <<= 1) { s += __shfl_xor(s, m); s2 += __shfl_xor(s2, m); }
  __shared__ float ps[4], ps2[4];
  const int wid = tid >> 6, lane = tid & 63;
  if (lane == 0) { ps[wid] = s; ps2[wid] = s2; }
  __syncthreads();
  s = ps[0] + ps[1] + ps[2] + ps[3];
  s2 = ps2[0] + ps2[1] + ps2[2] + ps2[3];
  const float mu = s * (1.0f / 1024.0f);
  const float rstd = rsqrtf(s2 * (1.0f / 1024.0f) - mu * mu + 1e-5f);
  f32x4 g4 = *(const f32x4*)(gam + tid * 4);
  f32x4 b4 = *(const f32x4*)(bet + tid * 4);
  u16x4 ov;
  #pragma unroll
  for (int j = 0; j < 4; j++) ov[j] = f2bf((v[j] - mu) * rstd * g4[j] + b4[j]);
  *(u16x4*)(o + (size_t)row * 1024 + tid * 4) = ov;
}

// -------- transpose+convert: W[K][N] f32 -> WT[N][K] bf16 (64x64 LDS tiles) --------
__global__ __launch_bounds__(256) void transpose_kernel(
    const float* __restrict__ W, unsigned short* __restrict__ WT, int K, int N)
{
  __shared__ float tile[64][65];
  const int n0 = blockIdx.x * 64, k0 = blockIdx.y * 64;
  const int c = threadIdx.x & 63, r0 = threadIdx.x >> 6;
  #pragma unroll
  for (int r = r0; r < 64; r += 4)
    tile[r][c] = W[(size_t)(k0 + r) * N + n0 + c];
  __syncthreads();
  #pragma unroll
  for (int r = r0; r < 64; r += 4)
    WT[(size_t)(n0 + r) * K + k0 + c] = f2bf(tile[c][r]);
}

// --- 128x256 GEMM, BK=64, XOR-swizzled LDS, 3-slot ring, ONE barrier/K-tile ---
// MODE 0: out bf16, cols<1024 pre-scaled by 0.125*log2e (Q for attn);
// MODE 1: out f32 = v + resid; MODE 2: out bf16 = gelu(v)
template <int MODE>
__global__ __launch_bounds__(512) void gemm8_kernel(
    const unsigned short* __restrict__ A, const unsigned short* __restrict__ WT,
    const float* __restrict__ bias, const float* resid, void* outp,
    int M, int N, int K)
{
  __shared__ unsigned short lds[3 * 24576];   // slot: A 128x64 (16KB) + B 256x64 (32KB)
  const int tid = threadIdx.x;
  const int lane = tid & 63, wid = tid >> 6;
  const int l15 = lane & 15, l4 = lane >> 4;
  const int wm = wid >> 2, wn = wid & 3;
  const int tiles_n = N >> 8;
  const int cpx = gridDim.x >> 3;
  const int id = (blockIdx.x & 7) * cpx + (blockIdx.x >> 3);
  const int bm = id / tiles_n, bn = id % tiles_n;
  const int NT = K >> 6;

  const int srow = tid >> 3;
  const int scol = ((tid & 7) ^ (srow & 7)) * 8;
  const unsigned short* Asrc = A  + (size_t)(bm * 128 + srow) * K + scol;
  const unsigned short* Bsrc = WT + (size_t)(bn * 256 + srow) * K + scol;
  const size_t j64 = (size_t)64 * K;
  const int dwave = wid * 1024;

#define STAGE(t_, ss_) do { \
    char* base_ = (char*)lds + (ss_) * 49152 + dwave; \
    const unsigned short* sA_ = Asrc + (size_t)(t_) * 64; \
    const unsigned short* sB_ = Bsrc + (size_t)(t_) * 64; \
    gload_lds16(sA_,            base_); \
    gload_lds16(sA_ + j64,      base_ + 8192); \
    gload_lds16(sB_,            base_ + 16384); \
    gload_lds16(sB_ + j64,      base_ + 16384 + 8192); \
    gload_lds16(sB_ + 2 * j64,  base_ + 16384 + 16384); \
    gload_lds16(sB_ + 3 * j64,  base_ + 16384 + 24576); \
  } while (0)

  f32x4 acc[4][4] = {};

  const int arow0 = wm * 64 + l15;
  const int brow0 = wn * 64 + l15;
  const int cswz = l15 & 7;

  STAGE(0, 0);
  STAGE(1, 1);
  asm volatile("s_waitcnt vmcnt(6)" ::: "memory");
  __builtin_amdgcn_s_barrier();

  int cs = 0, ss = 2;
  for (int t = 0; t < NT; ++t) {
    const unsigned short* sa = lds + cs * 24576;
    const unsigned short* sb = sa + 8192;
    s16x8 af[4][2], bf[4][2];
    #pragma unroll
    for (int mf = 0; mf < 4; ++mf)
      #pragma unroll
      for (int ks = 0; ks < 2; ++ks)
        af[mf][ks] = *(const s16x8*)&sa[(arow0 + mf * 16) * 64 + (((ks * 4 + l4) ^ cswz) * 8)];
    #pragma unroll
    for (int nf = 0; nf < 4; ++nf)
      #pragma unroll
      for (int ks = 0; ks < 2; ++ks)
        bf[nf][ks] = *(const s16x8*)&sb[(brow0 + nf * 16) * 64 + (((ks * 4 + l4) ^ cswz) * 8)];
    if (t + 2 < NT) STAGE(t + 2, ss);
    __builtin_amdgcn_s_setprio(1);
    #pragma unroll
    for (int mf = 0; mf < 4; ++mf)
      #pragma unroll
      for (int nf = 0; nf < 4; ++nf)
        #pragma unroll
        for (int ks = 0; ks < 2; ++ks)
          acc[mf][nf] = __builtin_amdgcn_mfma_f32_16x16x32_bf16(
              af[mf][ks], bf[nf][ks], acc[mf][nf], 0, 0, 0);
    __builtin_amdgcn_s_setprio(0);
    if (t + 2 < NT)      { asm volatile("s_waitcnt vmcnt(6)" ::: "memory"); }
    else if (t + 1 < NT) { asm volatile("s_waitcnt vmcnt(0)" ::: "memory"); }
    __builtin_amdgcn_s_barrier();
    cs = (cs == 2) ? 0 : cs + 1;
    ss = (ss == 2) ? 0 : ss + 1;
  }
#undef STAGE

  #pragma unroll
  for (int nf = 0; nf < 4; nf++) {
    const int col = bn * 256 + wn * 64 + nf * 16 + l15;
    const float bv = bias[col];
    const float qs = (MODE == 0 && col < 1024) ? 0.18033688f : 1.0f;  // Q pre-scale
    #pragma unroll
    for (int mf = 0; mf < 4; mf++) {
      #pragma unroll
      for (int r = 0; r < 4; r++) {
        const int row = bm * 128 + wm * 64 + mf * 16 + l4 * 4 + r;
        const size_t off = (size_t)row * N + col;
        float v = acc[mf][nf][r] + bv;
        if (MODE == 1) {
          ((float*)outp)[off] = v + resid[off];
        } else if (MODE == 2) {
          const float u = v + 0.044715f * v * v * v;
          const float e = exp2_asm(-2.3022010f * u);
          ((unsigned short*)outp)[off] = f2bf(v * rcp_asm(1.0f + e));
        } else {
          ((unsigned short*)outp)[off] = f2bf(v * qs);
        }
      }
    }
  }
}

// ---- causal flash attention (R11: 32x32 MFMA, adjacent pairing, NO reg squeeze) ----
// R10 post-mortem: launch_bounds(256,6) capped regs at ~85/wave -> accumulator
// spill to scratch (FETCH +300MB). R11 reverts to (256,4) (128 regs/wave, no
// spill) and keeps adjacent pairing qA=2pid, qB=2pid+1 (272 vs 392 rounds).
__global__ __launch_bounds__(256, 4) void attn_kernel(
    const unsigned short* __restrict__ qkv, unsigned short* __restrict__ outb)
{
  __shared__ unsigned short Ks[2][64 * 64];       // [kv][d^((kv&7)<<3)], double-buffered
  __shared__ unsigned short Vt[64 * 64];          // [d][kv^(((d>>2)&7)<<3)]
  __shared__ float alf[4][32];                    // per-wave alpha/invl transpose slot
  const int pid = blockIdx.x;                     // 0..15
  const int qA = 2 * pid, qB = 2 * pid + 1;       // adjacent q-tile pair
  const int bh = blockIdx.y;
  const int b = bh >> 4, h = bh & 15;
  const int tid = threadIdx.x, lane = tid & 63, wid = tid >> 6;
  const int l31 = lane & 31, hi = lane >> 5;
  const int myq = (wid < 2) ? qA : qB;
  const int qbase = myq * 64 + (wid & 1) * 32;    // first of this wave's 32 rows
  const size_t base = (size_t)b * 2048 * 3072 + (size_t)h * 64;
  const unsigned short* Qb = qkv + base;
  const unsigned short* Kb = qkv + base + 1024;
  const unsigned short* Vb = qkv + base + 2048;

  // Q fragments: chunk c -> Q[qbase+l31][c*16 + hi*8 .. +8] (pre-scaled upstream)
  s16x8 qf[4];
  {
    const unsigned short* qr = Qb + (size_t)(qbase + l31) * 3072 + hi * 8;
    qf[0] = *(const s16x8*)(qr);
    qf[1] = *(const s16x8*)(qr + 16);
    qf[2] = *(const s16x8*)(qr + 32);
    qf[3] = *(const s16x8*)(qr + 48);
  }

  // prologue: V(0) reg loads FIRST, then K(0) gload_lds (vmcnt counts rely on order)
  u16x4 vv[4];
  #pragma unroll
  for (int it = 0; it < 4; ++it) {
    const int cc = tid + 256 * it;
    vv[it] = *(const u16x4*)(Vb + (size_t)(cc >> 4) * 3072 + (cc & 15) * 4);
  }
  #pragma unroll
  for (int s = 0; s < 2; ++s) {
    const int c = s * 256 + tid;
    const int kv = c >> 3;
    const int dsrc = ((c & 7) * 8) ^ ((kv & 7) << 3);
    gload_lds16(Kb + (size_t)kv * 3072 + dsrc, &Ks[0][(size_t)(c & ~63) * 8]);
  }

  f32x16 o0 = {0,0,0,0,0,0,0,0,0,0,0,0,0,0,0,0};
  f32x16 o1 = {0,0,0,0,0,0,0,0,0,0,0,0,0,0,0,0};
  float m = -1e30f, lsum = 0.f;

  for (int kvb = 0; kvb <= qB; ++kvb) {
    const int cur = kvb & 1;
    const int kv0 = kvb * 64;
    __builtin_amdgcn_s_barrier();                 // #1: prev tile fully consumed
    asm volatile("s_waitcnt vmcnt(2)" ::: "memory");   // V(kvb) regs landed; K(kvb) flying
    #pragma unroll
    for (int it = 0; it < 4; ++it) {
      const int cc = tid + 256 * it;
      const int vkv = cc >> 4;
      const int vd = (cc & 15) * 4;
      #pragma unroll
      for (int j = 0; j < 4; j++) {
        const int d = vd + j;
        Vt[d * 64 + (vkv ^ (((d >> 2) & 7) << 3))] = vv[it][j];
      }
    }
    if (kvb < qB) {
      #pragma unroll
      for (int it = 0; it < 4; ++it) {
        const int cc = tid + 256 * it;
        vv[it] = *(const u16x4*)(Vb + (size_t)((kvb + 1) * 64 + (cc >> 4)) * 3072 + (cc & 15) * 4);
      }
      asm volatile("s_waitcnt vmcnt(4)" ::: "memory");  // K(kvb) landed; V(kvb+1) flying
    } else {
      asm volatile("s_waitcnt vmcnt(0)" ::: "memory");
    }
    asm volatile("s_waitcnt lgkmcnt(0)" ::: "memory");  // Vt ds_writes drained
    __builtin_amdgcn_s_barrier();                 // #2: Ks[cur], Vt published
    if (kvb < qB) {
      #pragma unroll
      for (int s = 0; s < 2; ++s) {
        const int c = s * 256 + tid;
        const int kv = c >> 3;
        const int dsrc = ((c & 7) * 8) ^ ((kv & 7) << 3);
        gload_lds16(Kb + (size_t)((kvb + 1) * 64 + kv) * 3072 + dsrc,
                    &Ks[cur ^ 1][(size_t)(c & ~63) * 8]);
      }
    }

    if (kvb <= myq) {                             // wave-uniform compute gate
      const unsigned short* Kc = Ks[cur];
      // ---- QK^T: S^T[kv][q], lane=(q=l31,hi); reg r -> kv=(r&3)+8(r>>2)+4hi (+32 for s1)
      f32x16 s0 = {0,0,0,0,0,0,0,0,0,0,0,0,0,0,0,0};
      f32x16 s1 = {0,0,0,0,0,0,0,0,0,0,0,0,0,0,0,0};
      __builtin_amdgcn_s_setprio(1);
      #pragma unroll
      for (int c = 0; c < 4; ++c) {
        const int koff = ((2 * c + hi) ^ (l31 & 7)) * 8;
        s16x8 k0 = *(const s16x8*)&Kc[l31 * 64 + koff];
        s16x8 k1 = *(const s16x8*)&Kc[(32 + l31) * 64 + koff];
        s0 = __builtin_amdgcn_mfma_f32_32x32x16_bf16(k0, qf[c], s0, 0, 0, 0);
        s1 = __builtin_amdgcn_mfma_f32_32x32x16_bf16(k1, qf[c], s1, 0, 0, 0);
      }
      __builtin_amdgcn_s_setprio(0);
      // ---- mask (diagonal tiles only; wave-uniform branch)
      if (kv0 + 63 > qbase) {
        const int thr = qbase + l31 - kv0;        // mask if kv_local > thr
        #pragma unroll
        for (int r = 0; r < 16; ++r) {
          const int kvl = (r & 3) + 8 * (r >> 2) + 4 * hi;
          if (kvl > thr)      s0[r] = -3.0e38f;
          if (kvl + 32 > thr) s1[r] = -3.0e38f;
        }
      }
      // ---- online softmax (log2 domain; in-lane + one shfl)
      float mx = s0[0];
      #pragma unroll
      for (int r = 1; r < 16; ++r) mx = fmaxf(mx, s0[r]);
      #pragma unroll
      for (int r = 0; r < 16; ++r) mx = fmaxf(mx, s1[r]);
      mx = fmaxf(mx, __shfl_xor(mx, 32));
      const bool skip = __all(mx <= m + 11.5f);   // defer-max
      const float mnew = skip ? m : fmaxf(m, mx);
      float rsum = 0.f;
      #pragma unroll
      for (int r = 0; r < 16; ++r) { s0[r] = exp2_asm(s0[r] - mnew); rsum += s0[r]; }
      #pragma unroll
      for (int r = 0; r < 16; ++r) { s1[r] = exp2_asm(s1[r] - mnew); rsum += s1[r]; }
      rsum += __shfl_xor(rsum, 32);
      if (skip) {
        lsum += rsum;
      } else {
        const float alpha = exp2_asm(m - mnew);
        lsum = lsum * alpha + rsum;
        m = mnew;
        alf[wid][l31] = alpha;                    // transpose q->reg via LDS (rare)
        #pragma unroll
        for (int r = 0; r < 16; ++r) {
          const float ar = alf[wid][(r & 3) + 8 * (r >> 2) + 4 * hi];
          o0[r] *= ar; o1[r] *= ar;
        }
      }
      // ---- P -> PV A-fragments via pack + permlane32_swap (T12)
      s16x8 pa[4];
      #pragma unroll
      for (int kb = 0; kb < 2; ++kb) {
        #pragma unroll
        for (int cc = 0; cc < 2; ++cc) {
          const int rb = cc * 8;
          unsigned int X0, Y0, X1, Y1;
          if (kb == 0) {
            X0 = pk2(s0[rb + 0], s0[rb + 1]); Y0 = pk2(s0[rb + 4], s0[rb + 5]);
            X1 = pk2(s0[rb + 2], s0[rb + 3]); Y1 = pk2(s0[rb + 6], s0[rb + 7]);
          } else {
            X0 = pk2(s1[rb + 0], s1[rb + 1]); Y0 = pk2(s1[rb + 4], s1[rb + 5]);
            X1 = pk2(s1[rb + 2], s1[rb + 3]); Y1 = pk2(s1[rb + 6], s1[rb + 7]);
          }
          pl32swap(X0, Y0);                       // -> words w0, w2
          pl32swap(X1, Y1);                       // -> words w1, w3
          u32x4 w = {X0, X1, Y0, Y1};
          pa[kb * 2 + cc] = __builtin_bit_cast(s16x8, w);
        }
      }
      // ---- PV: O[q][d], lane=(d=l31,hi); A=pa (row=q,k=kv), B=Vt frag (col=d,k=kv)
      const int voff = l31 >> 2;                  // (d>>2)&7, same for both d-blocks
      __builtin_amdgcn_s_setprio(1);
      #pragma unroll
      for (int c = 0; c < 4; ++c) {
        const int off = ((2 * c + hi) ^ voff) * 8;
        s16x8 v0 = *(const s16x8*)&Vt[l31 * 64 + off];
        s16x8 v1 = *(const s16x8*)&Vt[(32 + l31) * 64 + off];
        o0 = __builtin_amdgcn_mfma_f32_32x32x16_bf16(pa[c], v0, o0, 0, 0, 0);
        o1 = __builtin_amdgcn_mfma_f32_32x32x16_bf16(pa[c], v1, o1, 0, 0, 0);
      }
      __builtin_amdgcn_s_setprio(0);
    }
  }

  // ---- normalize + write: lane=(d=l31,hi); q per reg via LDS transpose
  const float iv = rcp_asm(lsum);
  alf[wid][l31] = iv;
  unsigned short* ob = outb + ((size_t)b * 2048 + qbase) * 1024 + h * 64 + l31;
  #pragma unroll
  for (int r = 0; r < 16; ++r) {
    const int ql = (r & 3) + 8 * (r >> 2) + 4 * hi;
    const float ir = alf[wid][ql];
    ob[(size_t)ql * 1024]      = f2bf(o0[r] * ir);
    ob[(size_t)ql * 1024 + 32] = f2bf(o1[r] * ir);
  }
}

// ---------------- host ----------------
extern "C" void kernel_launch(void* const* d_in, const int* in_sizes, int n_in,
                              void* d_out, int out_size, void* d_ws, size_t ws_size,
                              hipStream_t stream) {
  const float* x      = (const float*)d_in[0];
  const float* ln1_g  = (const float*)d_in[1];
  const float* ln1_b  = (const float*)d_in[2];
  const float* qkv_w  = (const float*)d_in[3];
  const float* qkv_b  = (const float*)d_in[4];
  const float* proj_w = (const float*)d_in[5];
  const float* proj_b = (const float*)d_in[6];
  const float* ln2_g  = (const float*)d_in[7];
  const float* ln2_b  = (const float*)d_in[8];
  const float* ff1_w  = (const float*)d_in[9];
  const float* ff1_b  = (const float*)d_in[10];
  const float* ff2_w  = (const float*)d_in[11];
  const float* ff2_b  = (const float*)d_in[12];
  float* out = (float*)d_out;

  char* ws = (char*)d_ws;
  size_t off = 0;
  unsigned short* wbuf   = (unsigned short*)(ws + off); off += (size_t)4096 * 1024 * 2;  // 8 MiB
  unsigned short* hbuf   = (unsigned short*)(ws + off); off += (size_t)8192 * 1024 * 2;  // 16 MiB
  unsigned short* qkvbuf = (unsigned short*)(ws + off); off += (size_t)8192 * 3072 * 2;  // 48 MiB
  unsigned short* gbuf   = (unsigned short*)(ws + off);                                   // 64 MiB

  // ---- attention sublayer ----
  ln_kernel<<<8192, 256, 0, stream>>>(x, ln1_g, ln1_b, hbuf);
  transpose_kernel<<<dim3(3072 / 64, 1024 / 64), 256, 0, stream>>>(qkv_w, wbuf, 1024, 3072);
  gemm8_kernel<0><<<dim3(64 * 12), 512, 0, stream>>>(hbuf, wbuf, qkv_b, nullptr, qkvbuf,
                                                     8192, 3072, 1024);
  attn_kernel<<<dim3(16, 64), 256, 0, stream>>>(qkvbuf, hbuf);
  transpose_kernel<<<dim3(1024 / 64, 1024 / 64), 256, 0, stream>>>(proj_w, wbuf, 1024, 1024);
  gemm8_kernel<1><<<dim3(64 * 4), 512, 0, stream>>>(hbuf, wbuf, proj_b, x, out,
                                                    8192, 1024, 1024);   // x1 -> d_out (f32)
  // ---- MLP sublayer ----
  ln_kernel<<<8192, 256, 0, stream>>>(out, ln2_g, ln2_b, hbuf);
  transpose_kernel<<<dim3(4096 / 64, 1024 / 64), 256, 0, stream>>>(ff1_w, wbuf, 1024, 4096);
  gemm8_kernel<2><<<dim3(64 * 16), 512, 0, stream>>>(hbuf, wbuf, ff1_b, nullptr, gbuf,
                                                     8192, 4096, 1024);  // gelu
  transpose_kernel<<<dim3(1024 / 64, 4096 / 64), 256, 0, stream>>>(ff2_w, wbuf, 4096, 1024);
  gemm8_kernel<1><<<dim3(64 * 4), 512, 0, stream>>>(gbuf, wbuf, ff2_b, out, out,
                                                    8192, 1024, 4096);   // + x1 in-place
}

// Round 12
// 465.519 us; speedup vs baseline: 1.3642x; 1.0095x over previous
//
#include <hip/hip_runtime.h>

typedef __attribute__((ext_vector_type(4))) float f32x4;
typedef __attribute__((ext_vector_type(16))) float f32x16;
typedef __attribute__((ext_vector_type(8))) short s16x8;
typedef __attribute__((ext_vector_type(4))) unsigned short u16x4;
typedef __attribute__((ext_vector_type(4))) unsigned int u32x4;

#define DEV __device__ __forceinline__

DEV unsigned short f2bf(float f) {
  unsigned int u = __float_as_uint(f);
  return (unsigned short)((u + 0x7FFFu + ((u >> 16) & 1u)) >> 16);
}

DEV float exp2_asm(float x) {        // v_exp_f32: D = 2^S0
  float r; asm("v_exp_f32 %0, %1" : "=v"(r) : "v"(x)); return r;
}
DEV float rcp_asm(float x) {
  float r; asm("v_rcp_f32 %0, %1" : "=v"(r) : "v"(x)); return r;
}
// pack two f32 -> bf16x2 word (truncating; P bounded, tolerance-safe per R8)
DEV unsigned int pk2(float a, float b) {
  return (__float_as_uint(b) & 0xFFFF0000u) | (__float_as_uint(a) >> 16);
}
// v_permlane32_swap_b32: X.lanes[32:63] <-> Y.lanes[0:31]
DEV void pl32swap(unsigned int& x, unsigned int& y) {
  asm volatile("v_permlane32_swap_b32 %0, %1" : "+v"(x), "+v"(y));
}

DEV void gload_lds16(const void* g, void* l) {
  __builtin_amdgcn_global_load_lds(
      (const __attribute__((address_space(1))) unsigned int*)g,
      (__attribute__((address_space(3))) unsigned int*)l, 16, 0, 0);
}

// ---------------- LayerNorm: fp32 in -> bf16 out (rows of 1024) ----------------
__global__ __launch_bounds__(256) void ln_kernel(
    const float* __restrict__ x, const float* __restrict__ gam,
    const float* __restrict__ bet, unsigned short* __restrict__ o)
{
  const int row = blockIdx.x;
  const int tid = threadIdx.x;
  f32x4 v = *(const f32x4*)(x + (size_t)row * 1024 + tid * 4);
  float s = v[0] + v[1] + v[2] + v[3];
  float s2 = v[0]*v[0] + v[1]*v[1] + v[2]*v[2] + v[3]*v[3];
  #pragma unroll
  for (int m = 1; m < 64; m <<= 1) { s += __shfl_xor(s, m); s2 += __shfl_xor(s2, m); }
  __shared__ float ps[4], ps2[4];
  const int wid = tid >> 6, lane = tid & 63;
  if (lane == 0) { ps[wid] = s; ps2[wid] = s2; }
  __syncthreads();
  s = ps[0] + ps[1] + ps[2] + ps[3];
  s2 = ps2[0] + ps2[1] + ps2[2] + ps2[3];
  const float mu = s * (1.0f / 1024.0f);
  const float rstd = rsqrtf(s2 * (1.0f / 1024.0f) - mu * mu + 1e-5f);
  f32x4 g4 = *(const f32x4*)(gam + tid * 4);
  f32x4 b4 = *(const f32x4*)(bet + tid * 4);
  u16x4 ov;
  #pragma unroll
  for (int j = 0; j < 4; j++) ov[j] = f2bf((v[j] - mu) * rstd * g4[j] + b4[j]);
  *(u16x4*)(o + (size_t)row * 1024 + tid * 4) = ov;
}

// -------- transpose+convert: W[K][N] f32 -> WT[N][K] bf16 (64x64 LDS tiles) --------
__global__ __launch_bounds__(256) void transpose_kernel(
    const float* __restrict__ W, unsigned short* __restrict__ WT, int K, int N)
{
  __shared__ float tile[64][65];
  const int n0 = blockIdx.x * 64, k0 = blockIdx.y * 64;
  const int c = threadIdx.x & 63, r0 = threadIdx.x >> 6;
  #pragma unroll
  for (int r = r0; r < 64; r += 4)
    tile[r][c] = W[(size_t)(k0 + r) * N + n0 + c];
  __syncthreads();
  #pragma unroll
  for (int r = r0; r < 64; r += 4)
    WT[(size_t)(n0 + r) * K + k0 + c] = f2bf(tile[c][r]);
}

// --- 128x256 GEMM, BK=64, XOR-swizzled LDS, 3-slot ring, 4-PHASE schedule ---
// R12: K-tile split into 4 phases of 8 MFMA: phase = (ks, mf-pair). Per phase:
// {2-6 ds_read_b128; 1 stage chunk (2 gload_lds); barrier; lgkmcnt(0);
// sched_barrier; setprio(1); 8 MFMA; setprio(0); barrier}. vmcnt(6) only at
// tile end (T4: never 0 mid-loop). T2 swizzle + T5 setprio carried over.
// MODE 0: out bf16, cols<1024 pre-scaled by 0.125*log2e (Q for attn);
// MODE 1: out f32 = v + resid; MODE 2: out bf16 = gelu(v)
template <int MODE>
__global__ __launch_bounds__(512) void gemm8_kernel(
    const unsigned short* __restrict__ A, const unsigned short* __restrict__ WT,
    const float* __restrict__ bias, const float* resid, void* outp,
    int M, int N, int K)
{
  __shared__ unsigned short lds[3 * 24576];   // slot: A 128x64 (16KB) + B 256x64 (32KB)
  const int tid = threadIdx.x;
  const int lane = tid & 63, wid = tid >> 6;
  const int l15 = lane & 15, l4 = lane >> 4;
  const int wm = wid >> 2, wn = wid & 3;
  const int tiles_n = N >> 8;
  const int cpx = gridDim.x >> 3;
  const int id = (blockIdx.x & 7) * cpx + (blockIdx.x >> 3);
  const int bm = id / tiles_n, bn = id % tiles_n;
  const int NT = K >> 6;

  const int srow = tid >> 3;
  const int scol = ((tid & 7) ^ (srow & 7)) * 8;
  const unsigned short* Asrc = A  + (size_t)(bm * 128 + srow) * K + scol;
  const unsigned short* Bsrc = WT + (size_t)(bn * 256 + srow) * K + scol;
  const size_t j64 = (size_t)64 * K;
  const int dwave = wid * 1024;

#define STAGE_A(t_, ss_) do { \
    char* base_ = (char*)lds + (ss_) * 49152 + dwave; \
    const unsigned short* sA_ = Asrc + (size_t)(t_) * 64; \
    gload_lds16(sA_,       base_); \
    gload_lds16(sA_ + j64, base_ + 8192); \
  } while (0)
#define STAGE_B0(t_, ss_) do { \
    char* base_ = (char*)lds + (ss_) * 49152 + dwave + 16384; \
    const unsigned short* sB_ = Bsrc + (size_t)(t_) * 64; \
    gload_lds16(sB_,       base_); \
    gload_lds16(sB_ + j64, base_ + 8192); \
  } while (0)
#define STAGE_B1(t_, ss_) do { \
    char* base_ = (char*)lds + (ss_) * 49152 + dwave + 16384 + 16384; \
    const unsigned short* sB_ = Bsrc + 2 * j64 + (size_t)(t_) * 64; \
    gload_lds16(sB_,       base_); \
    gload_lds16(sB_ + j64, base_ + 8192); \
  } while (0)

  f32x4 acc[4][4] = {};

  const int arow0 = wm * 64 + l15;
  const int brow0 = wn * 64 + l15;
  const int cswz = l15 & 7;

#define RDA(mf_, ks_) (*(const s16x8*)&sa[(arow0 + (mf_) * 16) * 64 + ((((ks_) * 4 + l4) ^ cswz) * 8)])
#define RDB(nf_, ks_) (*(const s16x8*)&sb[(brow0 + (nf_) * 16) * 64 + ((((ks_) * 4 + l4) ^ cswz) * 8)])
#define PH_SYNC  __builtin_amdgcn_s_barrier(); \
                 asm volatile("s_waitcnt lgkmcnt(0)" ::: "memory"); \
                 __builtin_amdgcn_sched_barrier(0)

  // prologue: stage tiles 0,1 (12 loads); wait tile 0 (oldest 6)
  STAGE_A(0, 0); STAGE_B0(0, 0); STAGE_B1(0, 0);
  STAGE_A(1, 1); STAGE_B0(1, 1); STAGE_B1(1, 1);
  asm volatile("s_waitcnt vmcnt(6)" ::: "memory");
  __builtin_amdgcn_s_barrier();

  int cs = 0, ss = 2;
  for (int t = 0; t < NT; ++t) {
    const unsigned short* sa = lds + cs * 24576;
    const unsigned short* sb = sa + 8192;
    const bool pf = (t + 2 < NT);
    s16x8 afx[2], bfx[4];
    // ---- phase 0: ks=0, mf={0,1}
    afx[0] = RDA(0, 0); afx[1] = RDA(1, 0);
    bfx[0] = RDB(0, 0); bfx[1] = RDB(1, 0); bfx[2] = RDB(2, 0); bfx[3] = RDB(3, 0);
    if (pf) STAGE_A(t + 2, ss);
    PH_SYNC;
    __builtin_amdgcn_s_setprio(1);
    #pragma unroll
    for (int nf = 0; nf < 4; ++nf) {
      acc[0][nf] = __builtin_amdgcn_mfma_f32_16x16x32_bf16(afx[0], bfx[nf], acc[0][nf], 0, 0, 0);
      acc[1][nf] = __builtin_amdgcn_mfma_f32_16x16x32_bf16(afx[1], bfx[nf], acc[1][nf], 0, 0, 0);
    }
    __builtin_amdgcn_s_setprio(0);
    __builtin_amdgcn_s_barrier();
    // ---- phase 1: ks=0, mf={2,3}
    afx[0] = RDA(2, 0); afx[1] = RDA(3, 0);
    if (pf) STAGE_B0(t + 2, ss);
    PH_SYNC;
    __builtin_amdgcn_s_setprio(1);
    #pragma unroll
    for (int nf = 0; nf < 4; ++nf) {
      acc[2][nf] = __builtin_amdgcn_mfma_f32_16x16x32_bf16(afx[0], bfx[nf], acc[2][nf], 0, 0, 0);
      acc[3][nf] = __builtin_amdgcn_mfma_f32_16x16x32_bf16(afx[1], bfx[nf], acc[3][nf], 0, 0, 0);
    }
    __builtin_amdgcn_s_setprio(0);
    __builtin_amdgcn_s_barrier();
    // ---- phase 2: ks=1, mf={0,1}
    afx[0] = RDA(0, 1); afx[1] = RDA(1, 1);
    bfx[0] = RDB(0, 1); bfx[1] = RDB(1, 1); bfx[2] = RDB(2, 1); bfx[3] = RDB(3, 1);
    if (pf) STAGE_B1(t + 2, ss);
    PH_SYNC;
    __builtin_amdgcn_s_setprio(1);
    #pragma unroll
    for (int nf = 0; nf < 4; ++nf) {
      acc[0][nf] = __builtin_amdgcn_mfma_f32_16x16x32_bf16(afx[0], bfx[nf], acc[0][nf], 0, 0, 0);
      acc[1][nf] = __builtin_amdgcn_mfma_f32_16x16x32_bf16(afx[1], bfx[nf], acc[1][nf], 0, 0, 0);
    }
    __builtin_amdgcn_s_setprio(0);
    __builtin_amdgcn_s_barrier();
    // ---- phase 3: ks=1, mf={2,3}
    afx[0] = RDA(2, 1); afx[1] = RDA(3, 1);
    PH_SYNC;
    __builtin_amdgcn_s_setprio(1);
    #pragma unroll
    for (int nf = 0; nf < 4; ++nf) {
      acc[2][nf] = __builtin_amdgcn_mfma_f32_16x16x32_bf16(afx[0], bfx[nf], acc[2][nf], 0, 0, 0);
      acc[3][nf] = __builtin_amdgcn_mfma_f32_16x16x32_bf16(afx[1], bfx[nf], acc[3][nf], 0, 0, 0);
    }
    __builtin_amdgcn_s_setprio(0);
    if (pf)                { asm volatile("s_waitcnt vmcnt(6)" ::: "memory"); }
    else if (t + 1 < NT)   { asm volatile("s_waitcnt vmcnt(0)" ::: "memory"); }
    __builtin_amdgcn_s_barrier();
    cs = (cs == 2) ? 0 : cs + 1;
    ss = (ss == 2) ? 0 : ss + 1;
  }
#undef STAGE_A
#undef STAGE_B0
#undef STAGE_B1
#undef RDA
#undef RDB
#undef PH_SYNC

  #pragma unroll
  for (int nf = 0; nf < 4; nf++) {
    const int col = bn * 256 + wn * 64 + nf * 16 + l15;
    const float bv = bias[col];
    const float qs = (MODE == 0 && col < 1024) ? 0.18033688f : 1.0f;  // Q pre-scale
    #pragma unroll
    for (int mf = 0; mf < 4; mf++) {
      #pragma unroll
      for (int r = 0; r < 4; r++) {
        const int row = bm * 128 + wm * 64 + mf * 16 + l4 * 4 + r;
        const size_t off = (size_t)row * N + col;
        float v = acc[mf][nf][r] + bv;
        if (MODE == 1) {
          ((float*)outp)[off] = v + resid[off];
        } else if (MODE == 2) {
          const float u = v + 0.044715f * v * v * v;
          const float e = exp2_asm(-2.3022010f * u);
          ((unsigned short*)outp)[off] = f2bf(v * rcp_asm(1.0f + e));
        } else {
          ((unsigned short*)outp)[off] = f2bf(v * qs);
        }
      }
    }
  }
}

// ---- causal flash attention (R12 = R9 exact: 32x32 MFMA, FAR pairing, (256,4)) ----
__global__ __launch_bounds__(256, 4) void attn_kernel(
    const unsigned short* __restrict__ qkv, unsigned short* __restrict__ outb)
{
  __shared__ unsigned short Ks[2][64 * 64];       // [kv][d^((kv&7)<<3)], double-buffered
  __shared__ unsigned short Vt[64 * 64];          // [d][kv^(((d>>2)&7)<<3)]
  __shared__ float alf[4][32];                    // per-wave alpha/invl transpose slot
  const int pid = blockIdx.x;                     // 0..15
  const int qA = pid, qB = 31 - pid;              // far pairing (R9)
  const int bh = blockIdx.y;
  const int b = bh >> 4, h = bh & 15;
  const int tid = threadIdx.x, lane = tid & 63, wid = tid >> 6;
  const int l31 = lane & 31, hi = lane >> 5;
  const int myq = (wid < 2) ? qA : qB;
  const int qbase = myq * 64 + (wid & 1) * 32;    // first of this wave's 32 rows
  const size_t base = (size_t)b * 2048 * 3072 + (size_t)h * 64;
  const unsigned short* Qb = qkv + base;
  const unsigned short* Kb = qkv + base + 1024;
  const unsigned short* Vb = qkv + base + 2048;

  // Q fragments: chunk c -> Q[qbase+l31][c*16 + hi*8 .. +8] (pre-scaled upstream)
  s16x8 qf[4];
  {
    const unsigned short* qr = Qb + (size_t)(qbase + l31) * 3072 + hi * 8;
    qf[0] = *(const s16x8*)(qr);
    qf[1] = *(const s16x8*)(qr + 16);
    qf[2] = *(const s16x8*)(qr + 32);
    qf[3] = *(const s16x8*)(qr + 48);
  }

  // prologue: V(0) reg loads FIRST, then K(0) gload_lds (vmcnt counts rely on order)
  u16x4 vv[4];
  #pragma unroll
  for (int it = 0; it < 4; ++it) {
    const int cc = tid + 256 * it;
    vv[it] = *(const u16x4*)(Vb + (size_t)(cc >> 4) * 3072 + (cc & 15) * 4);
  }
  #pragma unroll
  for (int s = 0; s < 2; ++s) {
    const int c = s * 256 + tid;
    const int kv = c >> 3;
    const int dsrc = ((c & 7) * 8) ^ ((kv & 7) << 3);
    gload_lds16(Kb + (size_t)kv * 3072 + dsrc, &Ks[0][(size_t)(c & ~63) * 8]);
  }

  f32x16 o0 = {0,0,0,0,0,0,0,0,0,0,0,0,0,0,0,0};
  f32x16 o1 = {0,0,0,0,0,0,0,0,0,0,0,0,0,0,0,0};
  float m = -1e30f, lsum = 0.f;

  for (int kvb = 0; kvb <= qB; ++kvb) {
    const int cur = kvb & 1;
    const int kv0 = kvb * 64;
    __builtin_amdgcn_s_barrier();                 // #1: prev tile fully consumed
    asm volatile("s_waitcnt vmcnt(2)" ::: "memory");   // V(kvb) regs landed; K(kvb) flying
    #pragma unroll
    for (int it = 0; it < 4; ++it) {
      const int cc = tid + 256 * it;
      const int vkv = cc >> 4;
      const int vd = (cc & 15) * 4;
      #pragma unroll
      for (int j = 0; j < 4; j++) {
        const int d = vd + j;
        Vt[d * 64 + (vkv ^ (((d >> 2) & 7) << 3))] = vv[it][j];
      }
    }
    if (kvb < qB) {
      #pragma unroll
      for (int it = 0; it < 4; ++it) {
        const int cc = tid + 256 * it;
        vv[it] = *(const u16x4*)(Vb + (size_t)((kvb + 1) * 64 + (cc >> 4)) * 3072 + (cc & 15) * 4);
      }
      asm volatile("s_waitcnt vmcnt(4)" ::: "memory");  // K(kvb) landed; V(kvb+1) flying
    } else {
      asm volatile("s_waitcnt vmcnt(0)" ::: "memory");
    }
    asm volatile("s_waitcnt lgkmcnt(0)" ::: "memory");  // Vt ds_writes drained
    __builtin_amdgcn_s_barrier();                 // #2: Ks[cur], Vt published
    if (kvb < qB) {
      #pragma unroll
      for (int s = 0; s < 2; ++s) {
        const int c = s * 256 + tid;
        const int kv = c >> 3;
        const int dsrc = ((c & 7) * 8) ^ ((kv & 7) << 3);
        gload_lds16(Kb + (size_t)((kvb + 1) * 64 + kv) * 3072 + dsrc,
                    &Ks[cur ^ 1][(size_t)(c & ~63) * 8]);
      }
    }

    if (kvb <= myq) {                             // wave-uniform compute gate
      const unsigned short* Kc = Ks[cur];
      f32x16 s0 = {0,0,0,0,0,0,0,0,0,0,0,0,0,0,0,0};
      f32x16 s1 = {0,0,0,0,0,0,0,0,0,0,0,0,0,0,0,0};
      __builtin_amdgcn_s_setprio(1);
      #pragma unroll
      for (int c = 0; c < 4; ++c) {
        const int koff = ((2 * c + hi) ^ (l31 & 7)) * 8;
        s16x8 k0 = *(const s16x8*)&Kc[l31 * 64 + koff];
        s16x8 k1 = *(const s16x8*)&Kc[(32 + l31) * 64 + koff];
        s0 = __builtin_amdgcn_mfma_f32_32x32x16_bf16(k0, qf[c], s0, 0, 0, 0);
        s1 = __builtin_amdgcn_mfma_f32_32x32x16_bf16(k1, qf[c], s1, 0, 0, 0);
      }
      __builtin_amdgcn_s_setprio(0);
      if (kv0 + 63 > qbase) {                     // diagonal tiles only
        const int thr = qbase + l31 - kv0;
        #pragma unroll
        for (int r = 0; r < 16; ++r) {
          const int kvl = (r & 3) + 8 * (r >> 2) + 4 * hi;
          if (kvl > thr)      s0[r] = -3.0e38f;
          if (kvl + 32 > thr) s1[r] = -3.0e38f;
        }
      }
      float mx = s0[0];
      #pragma unroll
      for (int r = 1; r < 16; ++r) mx = fmaxf(mx, s0[r]);
      #pragma unroll
      for (int r = 0; r < 16; ++r) mx = fmaxf(mx, s1[r]);
      mx = fmaxf(mx, __shfl_xor(mx, 32));
      const bool skip = __all(mx <= m + 11.5f);   // defer-max
      const float mnew = skip ? m : fmaxf(m, mx);
      float rsum = 0.f;
      #pragma unroll
      for (int r = 0; r < 16; ++r) { s0[r] = exp2_asm(s0[r] - mnew); rsum += s0[r]; }
      #pragma unroll
      for (int r = 0; r < 16; ++r) { s1[r] = exp2_asm(s1[r] - mnew); rsum += s1[r]; }
      rsum += __shfl_xor(rsum, 32);
      if (skip) {
        lsum += rsum;
      } else {
        const float alpha = exp2_asm(m - mnew);
        lsum = lsum * alpha + rsum;
        m = mnew;
        alf[wid][l31] = alpha;                    // transpose q->reg via LDS (rare)
        #pragma unroll
        for (int r = 0; r < 16; ++r) {
          const float ar = alf[wid][(r & 3) + 8 * (r >> 2) + 4 * hi];
          o0[r] *= ar; o1[r] *= ar;
        }
      }
      s16x8 pa[4];
      #pragma unroll
      for (int kb = 0; kb < 2; ++kb) {
        #pragma unroll
        for (int cc = 0; cc < 2; ++cc) {
          const int rb = cc * 8;
          unsigned int X0, Y0, X1, Y1;
          if (kb == 0) {
            X0 = pk2(s0[rb + 0], s0[rb + 1]); Y0 = pk2(s0[rb + 4], s0[rb + 5]);
            X1 = pk2(s0[rb + 2], s0[rb + 3]); Y1 = pk2(s0[rb + 6], s0[rb + 7]);
          } else {
            X0 = pk2(s1[rb + 0], s1[rb + 1]); Y0 = pk2(s1[rb + 4], s1[rb + 5]);
            X1 = pk2(s1[rb + 2], s1[rb + 3]); Y1 = pk2(s1[rb + 6], s1[rb + 7]);
          }
          pl32swap(X0, Y0);                       // -> words w0, w2
          pl32swap(X1, Y1);                       // -> words w1, w3
          u32x4 w = {X0, X1, Y0, Y1};
          pa[kb * 2 + cc] = __builtin_bit_cast(s16x8, w);
        }
      }
      const int voff = l31 >> 2;
      __builtin_amdgcn_s_setprio(1);
      #pragma unroll
      for (int c = 0; c < 4; ++c) {
        const int off = ((2 * c + hi) ^ voff) * 8;
        s16x8 v0 = *(const s16x8*)&Vt[l31 * 64 + off];
        s16x8 v1 = *(const s16x8*)&Vt[(32 + l31) * 64 + off];
        o0 = __builtin_amdgcn_mfma_f32_32x32x16_bf16(pa[c], v0, o0, 0, 0, 0);
        o1 = __builtin_amdgcn_mfma_f32_32x32x16_bf16(pa[c], v1, o1, 0, 0, 0);
      }
      __builtin_amdgcn_s_setprio(0);
    }
  }

  // ---- normalize + write: lane=(d=l31,hi); q per reg via LDS transpose
  const float iv = rcp_asm(lsum);
  alf[wid][l31] = iv;
  unsigned short* ob = outb + ((size_t)b * 2048 + qbase) * 1024 + h * 64 + l31;
  #pragma unroll
  for (int r = 0; r < 16; ++r) {
    const int ql = (r & 3) + 8 * (r >> 2) + 4 * hi;
    const float ir = alf[wid][ql];
    ob[(size_t)ql * 1024]      = f2bf(o0[r] * ir);
    ob[(size_t)ql * 1024 + 32] = f2bf(o1[r] * ir);
  }
}

// ---------------- host ----------------
extern "C" void kernel_launch(void* const* d_in, const int* in_sizes, int n_in,
                              void* d_out, int out_size, void* d_ws, size_t ws_size,
                              hipStream_t stream) {
  const float* x      = (const float*)d_in[0];
  const float* ln1_g  = (const float*)d_in[1];
  const float* ln1_b  = (const float*)d_in[2];
  const float* qkv_w  = (const float*)d_in[3];
  const float* qkv_b  = (const float*)d_in[4];
  const float* proj_w = (const float*)d_in[5];
  const float* proj_b = (const float*)d_in[6];
  const float* ln2_g  = (const float*)d_in[7];
  const float* ln2_b  = (const float*)d_in[8];
  const float* ff1_w  = (const float*)d_in[9];
  const float* ff1_b  = (const float*)d_in[10];
  const float* ff2_w  = (const float*)d_in[11];
  const float* ff2_b  = (const float*)d_in[12];
  float* out = (float*)d_out;

  char* ws = (char*)d_ws;
  size_t off = 0;
  unsigned short* wbuf   = (unsigned short*)(ws + off); off += (size_t)4096 * 1024 * 2;  // 8 MiB
  unsigned short* hbuf   = (unsigned short*)(ws + off); off += (size_t)8192 * 1024 * 2;  // 16 MiB
  unsigned short* qkvbuf = (unsigned short*)(ws + off); off += (size_t)8192 * 3072 * 2;  // 48 MiB
  unsigned short* gbuf   = (unsigned short*)(ws + off);                                   // 64 MiB

  // ---- attention sublayer ----
  ln_kernel<<<8192, 256, 0, stream>>>(x, ln1_g, ln1_b, hbuf);
  transpose_kernel<<<dim3(3072 / 64, 1024 / 64), 256, 0, stream>>>(qkv_w, wbuf, 1024, 3072);
  gemm8_kernel<0><<<dim3(64 * 12), 512, 0, stream>>>(hbuf, wbuf, qkv_b, nullptr, qkvbuf,
                                                     8192, 3072, 1024);
  attn_kernel<<<dim3(16, 64), 256, 0, stream>>>(qkvbuf, hbuf);
  transpose_kernel<<<dim3(1024 / 64, 1024 / 64), 256, 0, stream>>>(proj_w, wbuf, 1024, 1024);
  gemm8_kernel<1><<<dim3(64 * 4), 512, 0, stream>>>(hbuf, wbuf, proj_b, x, out,
                                                    8192, 1024, 1024);   // x1 -> d_out (f32)
  // ---- MLP sublayer ----
  ln_kernel<<<8192, 256, 0, stream>>>(out, ln2_g, ln2_b, hbuf);
  transpose_kernel<<<dim3(4096 / 64, 1024 / 64), 256, 0, stream>>>(ff1_w, wbuf, 1024, 4096);
  gemm8_kernel<2><<<dim3(64 * 16), 512, 0, stream>>>(hbuf, wbuf, ff1_b, nullptr, gbuf,
                                                     8192, 4096, 1024);  // gelu
  transpose_kernel<<<dim3(1024 / 64, 4096 / 64), 256, 0, stream>>>(ff2_w, wbuf, 4096, 1024);
  gemm8_kernel<1><<<dim3(64 * 4), 512, 0, stream>>>(gbuf, wbuf, ff2_b, out, out,
                                                    8192, 1024, 4096);   // + x1 in-place
}

// Round 14
// 446.802 us; speedup vs baseline: 1.4213x; 1.0419x over previous
//
#include <hip/hip_runtime.h>

typedef __attribute__((ext_vector_type(4))) float f32x4;
typedef __attribute__((ext_vector_type(16))) float f32x16;
typedef __attribute__((ext_vector_type(8))) short s16x8;
typedef __attribute__((ext_vector_type(4))) unsigned short u16x4;
typedef __attribute__((ext_vector_type(4))) unsigned int u32x4;

#define DEV __device__ __forceinline__

DEV unsigned short f2bf(float f) {
  unsigned int u = __float_as_uint(f);
  return (unsigned short)((u + 0x7FFFu + ((u >> 16) & 1u)) >> 16);
}

DEV float exp2_asm(float x) {        // v_exp_f32: D = 2^S0
  float r; asm("v_exp_f32 %0, %1" : "=v"(r) : "v"(x)); return r;
}
DEV float rcp_asm(float x) {
  float r; asm("v_rcp_f32 %0, %1" : "=v"(r) : "v"(x)); return r;
}
// pack two f32 -> bf16x2 word (truncating; P bounded, tolerance-safe per R8)
DEV unsigned int pk2(float a, float b) {
  return (__float_as_uint(b) & 0xFFFF0000u) | (__float_as_uint(a) >> 16);
}
// v_permlane32_swap_b32: X.lanes[32:63] <-> Y.lanes[0:31]
DEV void pl32swap(unsigned int& x, unsigned int& y) {
  asm volatile("v_permlane32_swap_b32 %0, %1" : "+v"(x), "+v"(y));
}

DEV void gload_lds16(const void* g, void* l) {
  __builtin_amdgcn_global_load_lds(
      (const __attribute__((address_space(1))) unsigned int*)g,
      (__attribute__((address_space(3))) unsigned int*)l, 16, 0, 0);
}

// ---------------- LayerNorm: fp32 in -> bf16 out (rows of 1024) ----------------
__global__ __launch_bounds__(256) void ln_kernel(
    const float* __restrict__ x, const float* __restrict__ gam,
    const float* __restrict__ bet, unsigned short* __restrict__ o)
{
  const int row = blockIdx.x;
  const int tid = threadIdx.x;
  f32x4 v = *(const f32x4*)(x + (size_t)row * 1024 + tid * 4);
  float s = v[0] + v[1] + v[2] + v[3];
  float s2 = v[0]*v[0] + v[1]*v[1] + v[2]*v[2] + v[3]*v[3];
  #pragma unroll
  for (int m = 1; m < 64; m <<= 1) { s += __shfl_xor(s, m); s2 += __shfl_xor(s2, m); }
  __shared__ float ps[4], ps2[4];
  const int wid = tid >> 6, lane = tid & 63;
  if (lane == 0) { ps[wid] = s; ps2[wid] = s2; }
  __syncthreads();
  s = ps[0] + ps[1] + ps[2] + ps[3];
  s2 = ps2[0] + ps2[1] + ps2[2] + ps2[3];
  const float mu = s * (1.0f / 1024.0f);
  const float rstd = rsqrtf(s2 * (1.0f / 1024.0f) - mu * mu + 1e-5f);
  f32x4 g4 = *(const f32x4*)(gam + tid * 4);
  f32x4 b4 = *(const f32x4*)(bet + tid * 4);
  u16x4 ov;
  #pragma unroll
  for (int j = 0; j < 4; j++) ov[j] = f2bf((v[j] - mu) * rstd * g4[j] + b4[j]);
  *(u16x4*)(o + (size_t)row * 1024 + tid * 4) = ov;
}

// -------- transpose+convert: W[K][N] f32 -> WT[N][K] bf16 (64x64 LDS tiles) --------
__global__ __launch_bounds__(256) void transpose_kernel(
    const float* __restrict__ W, unsigned short* __restrict__ WT, int K, int N)
{
  __shared__ float tile[64][65];
  const int n0 = blockIdx.x * 64, k0 = blockIdx.y * 64;
  const int c = threadIdx.x & 63, r0 = threadIdx.x >> 6;
  #pragma unroll
  for (int r = r0; r < 64; r += 4)
    tile[r][c] = W[(size_t)(k0 + r) * N + n0 + c];
  __syncthreads();
  #pragma unroll
  for (int r = r0; r < 64; r += 4)
    WT[(size_t)(n0 + r) * K + k0 + c] = f2bf(tile[c][r]);
}

// --- 128xBN GEMM, BK=64, XOR-swizzled LDS, NSLOT-ring, ONE barrier/K-tile ---
// BN=256/NSLOT=3: R6-proven path (depth-2 prefetch, vmcnt(6)).
// BN=128/NSLOT=2: for N=1024 shapes -> grid 512 = 2 blocks/CU (64KB LDS);
//                 depth-1 prefetch, vmcnt(0) drain at tile end.
// STAGE line stride: each gload line = 512 thr x 16B = 8192 B of LDS -> B line
// k_ lands at +16384 + k_*8192 (R13 bug: used k_*16384 -> NaN).
// MODE 0: out bf16, cols<1024 pre-scaled by 0.125*log2e (Q for attn);
// MODE 1: out f32 = v + resid; MODE 2: out bf16 = gelu(v)
template <int MODE, int BN, int NSLOT>
__global__ __launch_bounds__(512) void gemm8_kernel(
    const unsigned short* __restrict__ A, const unsigned short* __restrict__ WT,
    const float* __restrict__ bias, const float* resid, void* outp,
    int M, int N, int K)
{
  constexpr int NB = BN / 64;                    // B 64-row groups / frags per wave
  constexpr int SLOT_SH = 8192 + BN * 64;        // shorts per slot (A 16KB + B)
  __shared__ unsigned short lds[NSLOT * SLOT_SH];
  const int tid = threadIdx.x;
  const int lane = tid & 63, wid = tid >> 6;
  const int l15 = lane & 15, l4 = lane >> 4;
  const int wm = wid >> 2, wn = wid & 3;
  const int tiles_n = N / BN;
  const int cpx = gridDim.x >> 3;
  const int id = (blockIdx.x & 7) * cpx + (blockIdx.x >> 3);
  const int bm = id / tiles_n, bn = id % tiles_n;
  const int NT = K >> 6;

  const int srow = tid >> 3;
  const int scol = ((tid & 7) ^ (srow & 7)) * 8;
  const unsigned short* Asrc = A  + (size_t)(bm * 128 + srow) * K + scol;
  const unsigned short* Bsrc = WT + (size_t)(bn * BN + srow) * K + scol;
  const size_t j64 = (size_t)64 * K;
  const int dwave = wid * 1024;

#define STAGE(t_, ss_) do { \
    char* base_ = (char*)lds + (ss_) * (SLOT_SH * 2) + dwave; \
    const unsigned short* sA_ = Asrc + (size_t)(t_) * 64; \
    const unsigned short* sB_ = Bsrc + (size_t)(t_) * 64; \
    gload_lds16(sA_,       base_); \
    gload_lds16(sA_ + j64, base_ + 8192); \
    _Pragma("unroll") \
    for (int k_ = 0; k_ < NB; ++k_) \
      gload_lds16(sB_ + k_ * j64, base_ + 16384 + k_ * 8192); \
  } while (0)

  f32x4 acc[4][NB] = {};

  const int arow0 = wm * 64 + l15;
  const int brow0 = wn * (BN / 4) + l15;
  const int cswz = l15 & 7;

  if constexpr (NSLOT == 3) {
    STAGE(0, 0);
    STAGE(1, 1);
    asm volatile("s_waitcnt vmcnt(6)" ::: "memory");
  } else {
    STAGE(0, 0);
    asm volatile("s_waitcnt vmcnt(0)" ::: "memory");
  }
  __builtin_amdgcn_s_barrier();

  int cs = 0;
  for (int t = 0; t < NT; ++t) {
    const unsigned short* sa = lds + cs * SLOT_SH;
    const unsigned short* sb = sa + 8192;
    s16x8 af[4][2], bf[NB][2];
    #pragma unroll
    for (int mf = 0; mf < 4; ++mf)
      #pragma unroll
      for (int ks = 0; ks < 2; ++ks)
        af[mf][ks] = *(const s16x8*)&sa[(arow0 + mf * 16) * 64 + (((ks * 4 + l4) ^ cswz) * 8)];
    #pragma unroll
    for (int nf = 0; nf < NB; ++nf)
      #pragma unroll
      for (int ks = 0; ks < 2; ++ks)
        bf[nf][ks] = *(const s16x8*)&sb[(brow0 + nf * 16) * 64 + (((ks * 4 + l4) ^ cswz) * 8)];
    constexpr int D = NSLOT - 1;
    if (t + D < NT) {
      const int ss = (t + D) % NSLOT;
      STAGE(t + D, ss);
    }
    __builtin_amdgcn_s_setprio(1);
    #pragma unroll
    for (int mf = 0; mf < 4; ++mf)
      #pragma unroll
      for (int nf = 0; nf < NB; ++nf)
        #pragma unroll
        for (int ks = 0; ks < 2; ++ks)
          acc[mf][nf] = __builtin_amdgcn_mfma_f32_16x16x32_bf16(
              af[mf][ks], bf[nf][ks], acc[mf][nf], 0, 0, 0);
    __builtin_amdgcn_s_setprio(0);
    if constexpr (NSLOT == 3) {
      if (t + 2 < NT)      { asm volatile("s_waitcnt vmcnt(6)" ::: "memory"); }
      else if (t + 1 < NT) { asm volatile("s_waitcnt vmcnt(0)" ::: "memory"); }
    } else {
      if (t + 1 < NT)      { asm volatile("s_waitcnt vmcnt(0)" ::: "memory"); }
    }
    __builtin_amdgcn_s_barrier();
    cs = (cs + 1 == NSLOT) ? 0 : cs + 1;
  }
#undef STAGE

  #pragma unroll
  for (int nf = 0; nf < NB; nf++) {
    const int col = bn * BN + wn * (BN / 4) + nf * 16 + l15;
    const float bv = bias[col];
    const float qs = (MODE == 0 && col < 1024) ? 0.18033688f : 1.0f;  // Q pre-scale
    #pragma unroll
    for (int mf = 0; mf < 4; mf++) {
      #pragma unroll
      for (int r = 0; r < 4; r++) {
        const int row = bm * 128 + wm * 64 + mf * 16 + l4 * 4 + r;
        const size_t off = (size_t)row * N + col;
        float v = acc[mf][nf][r] + bv;
        if (MODE == 1) {
          ((float*)outp)[off] = v + resid[off];
        } else if (MODE == 2) {
          const float u = v + 0.044715f * v * v * v;
          const float e = exp2_asm(-2.3022010f * u);
          ((unsigned short*)outp)[off] = f2bf(v * rcp_asm(1.0f + e));
        } else {
          ((unsigned short*)outp)[off] = f2bf(v * qs);
        }
      }
    }
  }
}

// ---- causal flash attention (R14 = R12: 32x32 MFMA, FAR pairing, (256,4)) ----
__global__ __launch_bounds__(256, 4) void attn_kernel(
    const unsigned short* __restrict__ qkv, unsigned short* __restrict__ outb)
{
  __shared__ unsigned short Ks[2][64 * 64];       // [kv][d^((kv&7)<<3)], double-buffered
  __shared__ unsigned short Vt[64 * 64];          // [d][kv^(((d>>2)&7)<<3)]
  __shared__ float alf[4][32];                    // per-wave alpha/invl transpose slot
  const int pid = blockIdx.x;                     // 0..15
  const int qA = pid, qB = 31 - pid;              // far pairing (R9)
  const int bh = blockIdx.y;
  const int b = bh >> 4, h = bh & 15;
  const int tid = threadIdx.x, lane = tid & 63, wid = tid >> 6;
  const int l31 = lane & 31, hi = lane >> 5;
  const int myq = (wid < 2) ? qA : qB;
  const int qbase = myq * 64 + (wid & 1) * 32;    // first of this wave's 32 rows
  const size_t base = (size_t)b * 2048 * 3072 + (size_t)h * 64;
  const unsigned short* Qb = qkv + base;
  const unsigned short* Kb = qkv + base + 1024;
  const unsigned short* Vb = qkv + base + 2048;

  s16x8 qf[4];
  {
    const unsigned short* qr = Qb + (size_t)(qbase + l31) * 3072 + hi * 8;
    qf[0] = *(const s16x8*)(qr);
    qf[1] = *(const s16x8*)(qr + 16);
    qf[2] = *(const s16x8*)(qr + 32);
    qf[3] = *(const s16x8*)(qr + 48);
  }

  // prologue: V(0) reg loads FIRST, then K(0) gload_lds (vmcnt counts rely on order)
  u16x4 vv[4];
  #pragma unroll
  for (int it = 0; it < 4; ++it) {
    const int cc = tid + 256 * it;
    vv[it] = *(const u16x4*)(Vb + (size_t)(cc >> 4) * 3072 + (cc & 15) * 4);
  }
  #pragma unroll
  for (int s = 0; s < 2; ++s) {
    const int c = s * 256 + tid;
    const int kv = c >> 3;
    const int dsrc = ((c & 7) * 8) ^ ((kv & 7) << 3);
    gload_lds16(Kb + (size_t)kv * 3072 + dsrc, &Ks[0][(size_t)(c & ~63) * 8]);
  }

  f32x16 o0 = {0,0,0,0,0,0,0,0,0,0,0,0,0,0,0,0};
  f32x16 o1 = {0,0,0,0,0,0,0,0,0,0,0,0,0,0,0,0};
  float m = -1e30f, lsum = 0.f;

  for (int kvb = 0; kvb <= qB; ++kvb) {
    const int cur = kvb & 1;
    const int kv0 = kvb * 64;
    __builtin_amdgcn_s_barrier();                 // #1: prev tile fully consumed
    asm volatile("s_waitcnt vmcnt(2)" ::: "memory");   // V(kvb) regs landed; K(kvb) flying
    #pragma unroll
    for (int it = 0; it < 4; ++it) {
      const int cc = tid + 256 * it;
      const int vkv = cc >> 4;
      const int vd = (cc & 15) * 4;
      #pragma unroll
      for (int j = 0; j < 4; j++) {
        const int d = vd + j;
        Vt[d * 64 + (vkv ^ (((d >> 2) & 7) << 3))] = vv[it][j];
      }
    }
    if (kvb < qB) {
      #pragma unroll
      for (int it = 0; it < 4; ++it) {
        const int cc = tid + 256 * it;
        vv[it] = *(const u16x4*)(Vb + (size_t)((kvb + 1) * 64 + (cc >> 4)) * 3072 + (cc & 15) * 4);
      }
      asm volatile("s_waitcnt vmcnt(4)" ::: "memory");  // K(kvb) landed; V(kvb+1) flying
    } else {
      asm volatile("s_waitcnt vmcnt(0)" ::: "memory");
    }
    asm volatile("s_waitcnt lgkmcnt(0)" ::: "memory");  // Vt ds_writes drained
    __builtin_amdgcn_s_barrier();                 // #2: Ks[cur], Vt published
    if (kvb < qB) {
      #pragma unroll
      for (int s = 0; s < 2; ++s) {
        const int c = s * 256 + tid;
        const int kv = c >> 3;
        const int dsrc = ((c & 7) * 8) ^ ((kv & 7) << 3);
        gload_lds16(Kb + (size_t)((kvb + 1) * 64 + kv) * 3072 + dsrc,
                    &Ks[cur ^ 1][(size_t)(c & ~63) * 8]);
      }
    }

    if (kvb <= myq) {                             // wave-uniform compute gate
      const unsigned short* Kc = Ks[cur];
      f32x16 s0 = {0,0,0,0,0,0,0,0,0,0,0,0,0,0,0,0};
      f32x16 s1 = {0,0,0,0,0,0,0,0,0,0,0,0,0,0,0,0};
      __builtin_amdgcn_s_setprio(1);
      #pragma unroll
      for (int c = 0; c < 4; ++c) {
        const int koff = ((2 * c + hi) ^ (l31 & 7)) * 8;
        s16x8 k0 = *(const s16x8*)&Kc[l31 * 64 + koff];
        s16x8 k1 = *(const s16x8*)&Kc[(32 + l31) * 64 + koff];
        s0 = __builtin_amdgcn_mfma_f32_32x32x16_bf16(k0, qf[c], s0, 0, 0, 0);
        s1 = __builtin_amdgcn_mfma_f32_32x32x16_bf16(k1, qf[c], s1, 0, 0, 0);
      }
      __builtin_amdgcn_s_setprio(0);
      if (kv0 + 63 > qbase) {                     // diagonal tiles only
        const int thr = qbase + l31 - kv0;
        #pragma unroll
        for (int r = 0; r < 16; ++r) {
          const int kvl = (r & 3) + 8 * (r >> 2) + 4 * hi;
          if (kvl > thr)      s0[r] = -3.0e38f;
          if (kvl + 32 > thr) s1[r] = -3.0e38f;
        }
      }
      float mx = s0[0];
      #pragma unroll
      for (int r = 1; r < 16; ++r) mx = fmaxf(mx, s0[r]);
      #pragma unroll
      for (int r = 0; r < 16; ++r) mx = fmaxf(mx, s1[r]);
      mx = fmaxf(mx, __shfl_xor(mx, 32));
      const bool skip = __all(mx <= m + 11.5f);   // defer-max
      const float mnew = skip ? m : fmaxf(m, mx);
      float rsum = 0.f;
      #pragma unroll
      for (int r = 0; r < 16; ++r) { s0[r] = exp2_asm(s0[r] - mnew); rsum += s0[r]; }
      #pragma unroll
      for (int r = 0; r < 16; ++r) { s1[r] = exp2_asm(s1[r] - mnew); rsum += s1[r]; }
      rsum += __shfl_xor(rsum, 32);
      if (skip) {
        lsum += rsum;
      } else {
        const float alpha = exp2_asm(m - mnew);
        lsum = lsum * alpha + rsum;
        m = mnew;
        alf[wid][l31] = alpha;                    // transpose q->reg via LDS (rare)
        #pragma unroll
        for (int r = 0; r < 16; ++r) {
          const float ar = alf[wid][(r & 3) + 8 * (r >> 2) + 4 * hi];
          o0[r] *= ar; o1[r] *= ar;
        }
      }
      s16x8 pa[4];
      #pragma unroll
      for (int kb = 0; kb < 2; ++kb) {
        #pragma unroll
        for (int cc = 0; cc < 2; ++cc) {
          const int rb = cc * 8;
          unsigned int X0, Y0, X1, Y1;
          if (kb == 0) {
            X0 = pk2(s0[rb + 0], s0[rb + 1]); Y0 = pk2(s0[rb + 4], s0[rb + 5]);
            X1 = pk2(s0[rb + 2], s0[rb + 3]); Y1 = pk2(s0[rb + 6], s0[rb + 7]);
          } else {
            X0 = pk2(s1[rb + 0], s1[rb + 1]); Y0 = pk2(s1[rb + 4], s1[rb + 5]);
            X1 = pk2(s1[rb + 2], s1[rb + 3]); Y1 = pk2(s1[rb + 6], s1[rb + 7]);
          }
          pl32swap(X0, Y0);                       // -> words w0, w2
          pl32swap(X1, Y1);                       // -> words w1, w3
          u32x4 w = {X0, X1, Y0, Y1};
          pa[kb * 2 + cc] = __builtin_bit_cast(s16x8, w);
        }
      }
      const int voff = l31 >> 2;
      __builtin_amdgcn_s_setprio(1);
      #pragma unroll
      for (int c = 0; c < 4; ++c) {
        const int off = ((2 * c + hi) ^ voff) * 8;
        s16x8 v0 = *(const s16x8*)&Vt[l31 * 64 + off];
        s16x8 v1 = *(const s16x8*)&Vt[(32 + l31) * 64 + off];
        o0 = __builtin_amdgcn_mfma_f32_32x32x16_bf16(pa[c], v0, o0, 0, 0, 0);
        o1 = __builtin_amdgcn_mfma_f32_32x32x16_bf16(pa[c], v1, o1, 0, 0, 0);
      }
      __builtin_amdgcn_s_setprio(0);
    }
  }

  // ---- normalize + write: lane=(d=l31,hi); q per reg via LDS transpose
  const float iv = rcp_asm(lsum);
  alf[wid][l31] = iv;
  unsigned short* ob = outb + ((size_t)b * 2048 + qbase) * 1024 + h * 64 + l31;
  #pragma unroll
  for (int r = 0; r < 16; ++r) {
    const int ql = (r & 3) + 8 * (r >> 2) + 4 * hi;
    const float ir = alf[wid][ql];
    ob[(size_t)ql * 1024]      = f2bf(o0[r] * ir);
    ob[(size_t)ql * 1024 + 32] = f2bf(o1[r] * ir);
  }
}

// ---------------- host ----------------
extern "C" void kernel_launch(void* const* d_in, const int* in_sizes, int n_in,
                              void* d_out, int out_size, void* d_ws, size_t ws_size,
                              hipStream_t stream) {
  const float* x      = (const float*)d_in[0];
  const float* ln1_g  = (const float*)d_in[1];
  const float* ln1_b  = (const float*)d_in[2];
  const float* qkv_w  = (const float*)d_in[3];
  const float* qkv_b  = (const float*)d_in[4];
  const float* proj_w = (const float*)d_in[5];
  const float* proj_b = (const float*)d_in[6];
  const float* ln2_g  = (const float*)d_in[7];
  const float* ln2_b  = (const float*)d_in[8];
  const float* ff1_w  = (const float*)d_in[9];
  const float* ff1_b  = (const float*)d_in[10];
  const float* ff2_w  = (const float*)d_in[11];
  const float* ff2_b  = (const float*)d_in[12];
  float* out = (float*)d_out;

  char* ws = (char*)d_ws;
  size_t off = 0;
  unsigned short* wbuf   = (unsigned short*)(ws + off); off += (size_t)4096 * 1024 * 2;  // 8 MiB
  unsigned short* hbuf   = (unsigned short*)(ws + off); off += (size_t)8192 * 1024 * 2;  // 16 MiB
  unsigned short* qkvbuf = (unsigned short*)(ws + off); off += (size_t)8192 * 3072 * 2;  // 48 MiB
  unsigned short* gbuf   = (unsigned short*)(ws + off);                                   // 64 MiB

  // ---- attention sublayer ----
  ln_kernel<<<8192, 256, 0, stream>>>(x, ln1_g, ln1_b, hbuf);
  transpose_kernel<<<dim3(3072 / 64, 1024 / 64), 256, 0, stream>>>(qkv_w, wbuf, 1024, 3072);
  gemm8_kernel<0, 256, 3><<<dim3(64 * 12), 512, 0, stream>>>(hbuf, wbuf, qkv_b, nullptr,
                                                             qkvbuf, 8192, 3072, 1024);
  attn_kernel<<<dim3(16, 64), 256, 0, stream>>>(qkvbuf, hbuf);
  transpose_kernel<<<dim3(1024 / 64, 1024 / 64), 256, 0, stream>>>(proj_w, wbuf, 1024, 1024);
  gemm8_kernel<1, 128, 2><<<dim3(64 * 8), 512, 0, stream>>>(hbuf, wbuf, proj_b, x, out,
                                                            8192, 1024, 1024);   // x1 -> d_out
  // ---- MLP sublayer ----
  ln_kernel<<<8192, 256, 0, stream>>>(out, ln2_g, ln2_b, hbuf);
  transpose_kernel<<<dim3(4096 / 64, 1024 / 64), 256, 0, stream>>>(ff1_w, wbuf, 1024, 4096);
  gemm8_kernel<2, 256, 3><<<dim3(64 * 16), 512, 0, stream>>>(hbuf, wbuf, ff1_b, nullptr,
                                                             gbuf, 8192, 4096, 1024);  // gelu
  transpose_kernel<<<dim3(1024 / 64, 4096 / 64), 256, 0, stream>>>(ff2_w, wbuf, 4096, 1024);
  gemm8_kernel<1, 128, 2><<<dim3(64 * 8), 512, 0, stream>>>(gbuf, wbuf, ff2_b, out, out,
                                                            8192, 1024, 4096);   // + x1
}